// Round 10
// baseline (157.947 us; speedup 1.0000x reference)
//
#include <hip/hip_runtime.h>
#include <math.h>

#define BB 8
#define NCC 1024
#define NTT 1024
#define HH 128
#define DYY 32
#define LOG2E 1.44269504088896340736f

// LDS arena (floats):
//   yc0/yc1 [    0, 4096)  attn yc half-row tiles, 2 x 128n x 16d (8 KB each)
//   xc0/xc1 [ 4096, 4864)  attn xc tiles, 2 x 384
//   sigl    [ 4864, 4960)  sig*log2e for the block's 32 targets
//   hbuf    [ 4960, 9088)  MLP activations 32x129 (stride 129, conflict-free)
//   red     [ 9088,10624)  MLP L3 reduction scratch
// epilogue aliases [0, 9216) as sacc(16x32x17)+sl(512) after last tile barrier.
#define YCOFF 0
#define XCOFF 4096
#define SIGL 4864
#define HB 4960
#define RED 9088
#define SMEMN 10624
#define HSTRIDE 129

// ---------------- fused kernel, d-split for occupancy ----------------
// Grid 512 = (tg 0..255) x (dh 0..1); 512 threads. Block = 32 targets, 16 of
// the 32 output dims. MLP (phase 1) is computed redundantly in both dh-blocks
// (cheap: chip was 68% idle at r9's 1 block/CU). Phase 2 stages yc HALF-rows
// (16 floats) so LDS fits 2 blocks/CU -> 4 waves/SIMD (r9: grid 256 = 1
// block/CU = 2 waves/SIMD was the limiter, VALUBusy 32%).
// r5 lesson: software-pipeline the W stream (depth 8). r6 lesson: staging
// loads must be lane-varying or they scalarize. r7 lesson: no pointer arrays
// into __shared__.
__global__ __launch_bounds__(512) void k_fused(const float* __restrict__ xc,
                                               const float* __restrict__ yc,
                                               const float* __restrict__ xt,
                                               const float* __restrict__ W0,
                                               const float* __restrict__ b0,
                                               const float* __restrict__ W1,
                                               const float* __restrict__ b1,
                                               const float* __restrict__ W2,
                                               const float* __restrict__ b2,
                                               const float* __restrict__ W3,
                                               const float* __restrict__ b3,
                                               float* __restrict__ out) {
    const int tid = threadIdx.x;
    const int tg = blockIdx.x >> 1;      // target-group 0..255
    const int dh = blockIdx.x & 1;       // d-half 0..1
    const int t0 = tg * 32;
    const int b = tg >> 5;               // batch

    __shared__ float smem[SMEMN];        // 41.5 KB

    const float4* __restrict__ ycG = (const float4*)(yc + (size_t)b * NCC * DYY);
    const float4* __restrict__ xcG = (const float4*)(xc + (size_t)b * NCC * 3);

    // staging map: thread -> (n within tile, quarter of my 16-float half-row)
    const int sn = tid >> 2;             // 0..127
    const int sq = tid & 3;              // 0..3

    // ---- issue tile-0/1 staging loads now (land during MLP compute) ----
    float4 y0 = ycG[(size_t)sn * 8 + dh * 4 + sq];
    float4 y1 = ycG[(size_t)(128 + sn) * 8 + dh * 4 + sq];
    float4 xp0, xp1;
    if (tid < 96) { xp0 = xcG[tid]; xp1 = xcG[96 + tid]; }

    // ================= phase 1: MLP =================
    {
        const int jg = tid >> 5;         // 0..15 col-group (2 per wave)
        const int p = tid & 31;          // 0..31 point
        const int j0 = jg * 8;

        const float* xr = xt + (size_t)(t0 + p) * 3;
        float x0 = xr[0], x1 = xr[1], x2 = xr[2];
        float o[8];
#pragma unroll
        for (int jj = 0; jj < 8; ++jj) {
            int j = j0 + jj;
            float a = b0[j];
            a = fmaf(x0, W0[0 * HH + j], a);
            a = fmaf(x1, W0[1 * HH + j], a);
            a = fmaf(x2, W0[2 * HH + j], a);
            o[jj] = fmaxf(a, 0.f);
        }
#pragma unroll
        for (int jj = 0; jj < 8; ++jj) smem[HB + p * HSTRIDE + j0 + jj] = o[jj];

        // park attn tiles 0/1 (frees prefetch VGPRs)
        ((float4*)(smem + YCOFF))[tid] = y0;
        ((float4*)(smem + YCOFF + 2048))[tid] = y1;
        if (tid < 96) {
            ((float4*)(smem + XCOFF))[tid] = xp0;
            ((float4*)(smem + XCOFF + 384))[tid] = xp1;
        }
        __syncthreads();

        for (int l = 0; l < 2; ++l) {
            const float* __restrict__ W = (l == 0) ? W1 : W2;
            const float* __restrict__ bi = (l == 0) ? b1 : b2;
            const float4* __restrict__ Wv = (const float4*)W;
            float acc[8];
#pragma unroll
            for (int jj = 0; jj < 8; ++jj) acc[jj] = bi[j0 + jj];

            float4 wa[8], wb[8];
            float hv[8];
#pragma unroll
            for (int i = 0; i < 8; ++i) {
                wa[i] = Wv[i * 32 + jg * 2];
                wb[i] = Wv[i * 32 + jg * 2 + 1];
                hv[i] = smem[HB + p * HSTRIDE + i];
            }
            for (int k = 0; k < 120; k += 8) {
#pragma unroll
                for (int i = 0; i < 8; ++i) {
                    float4 ca = wa[i], cb = wb[i];
                    float ch = hv[i];
                    int kn = k + 8 + i;
                    wa[i] = Wv[kn * 32 + jg * 2];
                    wb[i] = Wv[kn * 32 + jg * 2 + 1];
                    hv[i] = smem[HB + p * HSTRIDE + kn];
                    acc[0] = fmaf(ch, ca.x, acc[0]);
                    acc[1] = fmaf(ch, ca.y, acc[1]);
                    acc[2] = fmaf(ch, ca.z, acc[2]);
                    acc[3] = fmaf(ch, ca.w, acc[3]);
                    acc[4] = fmaf(ch, cb.x, acc[4]);
                    acc[5] = fmaf(ch, cb.y, acc[5]);
                    acc[6] = fmaf(ch, cb.z, acc[6]);
                    acc[7] = fmaf(ch, cb.w, acc[7]);
                }
            }
#pragma unroll
            for (int i = 0; i < 8; ++i) {
                float4 ca = wa[i], cb = wb[i];
                float ch = hv[i];
                acc[0] = fmaf(ch, ca.x, acc[0]);
                acc[1] = fmaf(ch, ca.y, acc[1]);
                acc[2] = fmaf(ch, ca.z, acc[2]);
                acc[3] = fmaf(ch, ca.w, acc[3]);
                acc[4] = fmaf(ch, cb.x, acc[4]);
                acc[5] = fmaf(ch, cb.y, acc[5]);
                acc[6] = fmaf(ch, cb.z, acc[6]);
                acc[7] = fmaf(ch, cb.w, acc[7]);
            }
            __syncthreads();
#pragma unroll
            for (int jj = 0; jj < 8; ++jj) o[jj] = fmaxf(acc[jj], 0.f);
            if (l == 0) {
#pragma unroll
                for (int jj = 0; jj < 8; ++jj) smem[HB + p * HSTRIDE + j0 + jj] = o[jj];
                __syncthreads();
            }
        }

        // L3 + exp -> sig*log2e in LDS
        float p0 = 0.f, p1 = 0.f, p2 = 0.f;
#pragma unroll
        for (int jj = 0; jj < 8; ++jj) {
            int j = j0 + jj;
            p0 = fmaf(o[jj], W3[j * 3 + 0], p0);
            p1 = fmaf(o[jj], W3[j * 3 + 1], p1);
            p2 = fmaf(o[jj], W3[j * 3 + 2], p2);
        }
        smem[RED + (jg * 32 + p) * 3 + 0] = p0;
        smem[RED + (jg * 32 + p) * 3 + 1] = p1;
        smem[RED + (jg * 32 + p) * 3 + 2] = p2;
        __syncthreads();
        if (tid < 96) {
            int r = tid / 3, c = tid - r * 3;
            float v = b3[c];
#pragma unroll
            for (int g = 0; g < 16; ++g) v += smem[RED + (g * 32 + r) * 3 + c];
            smem[SIGL + r * 3 + c] = __expf(v) * LOG2E;
        }
        __syncthreads();
    }

    // ================= phase 2: attention (d-half dh) =================
    const int w = tid >> 6;          // 0..7 wave
    const int lane = tid & 63;
    const int tl = lane & 31;        // target within block
    const int ng = lane >> 5;        // 0..1 n-stream within wave

    const float s0 = smem[SIGL + tl * 3 + 0];
    const float s1 = smem[SIGL + tl * 3 + 1];
    const float s2 = smem[SIGL + tl * 3 + 2];
    const size_t t = (size_t)t0 + tl;
    const float a0 = xt[t * 3 + 0], a1 = xt[t * 3 + 1], a2 = xt[t * 3 + 2];

    float acc[16];
#pragma unroll
    for (int i = 0; i < 16; ++i) acc[i] = 0.f;
    float l = 0.f;

    for (int tile = 0; tile < 8; ++tile) {
        const int cur = tile & 1;
        float4 yn, xn;
        if (tile < 6) {                       // prefetch tile+2 (distance 2)
            yn = ycG[(size_t)((tile + 2) * 128 + sn) * 8 + dh * 4 + sq];
            if (tid < 96) xn = xcG[(tile + 2) * 96 + tid];
        }

        const float* yb = smem + YCOFF + cur * 2048;
        const float* xb = smem + XCOFF + cur * 384;
#pragma unroll
        for (int i = 0; i < 8; ++i) {
            const int nn = w * 16 + ng * 8 + i;
            float d0 = xb[nn * 3 + 0] - a0;
            float d1 = xb[nn * 3 + 1] - a1;
            float d2 = xb[nn * 3 + 2] - a2;
            float pp = fmaf(s0, d0 * d0, fmaf(s1, d1 * d1, s2 * (d2 * d2)));
            float e = exp2f(-pp);
            l += e;
            const float4* yv = (const float4*)(yb + nn * 16);
            float4 q0 = yv[0], q1 = yv[1], q2 = yv[2], q3 = yv[3];
            acc[0]  = fmaf(e, q0.x, acc[0]);
            acc[1]  = fmaf(e, q0.y, acc[1]);
            acc[2]  = fmaf(e, q0.z, acc[2]);
            acc[3]  = fmaf(e, q0.w, acc[3]);
            acc[4]  = fmaf(e, q1.x, acc[4]);
            acc[5]  = fmaf(e, q1.y, acc[5]);
            acc[6]  = fmaf(e, q1.z, acc[6]);
            acc[7]  = fmaf(e, q1.w, acc[7]);
            acc[8]  = fmaf(e, q2.x, acc[8]);
            acc[9]  = fmaf(e, q2.y, acc[9]);
            acc[10] = fmaf(e, q2.z, acc[10]);
            acc[11] = fmaf(e, q2.w, acc[11]);
            acc[12] = fmaf(e, q3.x, acc[12]);
            acc[13] = fmaf(e, q3.y, acc[13]);
            acc[14] = fmaf(e, q3.z, acc[14]);
            acc[15] = fmaf(e, q3.w, acc[15]);
        }
        __syncthreads();                      // tile reads done
        if (tile < 6) {
            ((float4*)(smem + YCOFF + cur * 2048))[tid] = yn;
            if (tid < 96) ((float4*)(smem + XCOFF + cur * 384))[tid] = xn;
            __syncthreads();
        }
    }

    // ---- combine 16 streams/target in LDS, normalize, write my d-half ----
    // sacc[(stream*32+tl)*17 + d] (8704 floats), sl at 8704 (512) — aliases arena.
    const int st = w * 2 + ng;               // 0..15
#pragma unroll
    for (int i = 0; i < 16; ++i)
        smem[(st * 32 + tl) * 17 + i] = acc[i];
    smem[8704 + st * 32 + tl] = l;
    __syncthreads();

    {
        const int rtl = tid >> 4, d = tid & 15;   // one output element per thread
        float s = 0.f, lsum = 0.f;
#pragma unroll
        for (int ss = 0; ss < 16; ++ss) {
            s += smem[(ss * 32 + rtl) * 17 + d];
            lsum += smem[8704 + ss * 32 + rtl];
        }
        out[(size_t)(t0 + rtl) * DYY + dh * 16 + d] = s / lsum;
    }
}

extern "C" void kernel_launch(void* const* d_in, const int* in_sizes, int n_in,
                              void* d_out, int out_size, void* d_ws, size_t ws_size,
                              hipStream_t stream) {
    const float* xc = (const float*)d_in[0];
    const float* yc = (const float*)d_in[1];
    const float* xt = (const float*)d_in[2];
    const float* W0 = (const float*)d_in[3];
    const float* b0 = (const float*)d_in[4];
    const float* W1 = (const float*)d_in[5];
    const float* b1 = (const float*)d_in[6];
    const float* W2 = (const float*)d_in[7];
    const float* b2 = (const float*)d_in[8];
    const float* W3 = (const float*)d_in[9];
    const float* b3 = (const float*)d_in[10];
    float* out = (float*)d_out;

    k_fused<<<dim3(BB * NTT / 32 * 2), dim3(512), 0, stream>>>(xc, yc, xt, W0, b0,
                                                               W1, b1, W2, b2, W3,
                                                               b3, out);
}